// Round 4
// baseline (1345.261 us; speedup 1.0000x reference)
//
#include <hip/hip_runtime.h>
#include <math.h>
#include <stdint.h>

#define D2 2048

typedef int v4i __attribute__((ext_vector_type(4)));

struct Ptrs8 { const float* p[8]; };
struct RowMap { int seg, jump, off; };

enum { QW_Q = 0, QW_OUT = 1, QW_ADDQ = 2, QW_ADDOUT = 3, QW_I = 4, QW_F = 5, QW_G = 6, QW_O = 7 };

__device__ __forceinline__ int rmap(RowMap m, int r) {
  return (r / m.seg) * m.jump + (r % m.seg) + m.off;
}

__device__ __forceinline__ void gload16(const void* g, void* l) {
  __builtin_amdgcn_global_load_lds((__attribute__((address_space(1))) void*)g,
                                   (__attribute__((address_space(3))) void*)l, 16, 0, 0);
}

__device__ __forceinline__ float fsig(float x) {
  return __builtin_amdgcn_rcpf(1.0f + __expf(-x));
}

// XCD-chunked bijective grid swizzle (nwg divisible by 8 for all our grids), n-fast
// within a chunk so one 256KB A-panel stays hot in each XCD's L2. nN == 16 always.
__device__ __forceinline__ void gswz(int nM, int& mb, int& nb) {
  int bid = blockIdx.x;
  int wg = (bid & 7) * (nM << 1) + (bid >> 3);
  mb = wg >> 4;
  nb = wg & 15;
}

// ---------------- weight quantization ----------------
__global__ __launch_bounds__(256) void k_wabs(Ptrs8 wsrc, double* part) {
  int m = blockIdx.y;
  const float4* w4 = (const float4*)(wsrc.p[m] + (size_t)blockIdx.x * 4096 + threadIdx.x * 16);
  double s = 0.0;
#pragma unroll
  for (int j = 0; j < 4; ++j) {
    float4 v = w4[j];
    s += (double)fabsf(v.x) + (double)fabsf(v.y) + (double)fabsf(v.z) + (double)fabsf(v.w);
  }
#pragma unroll
  for (int o = 32; o; o >>= 1) s += __shfl_down(s, o);
  __shared__ double red[4];
  if ((threadIdx.x & 63) == 0) red[threadIdx.x >> 6] = s;
  __syncthreads();
  if (threadIdx.x == 0) part[(size_t)m * 1024 + blockIdx.x] = red[0] + red[1] + red[2] + red[3];
}

__global__ __launch_bounds__(256) void k_wmean(const double* part, double* wqs, float* wmul) {
  int m = blockIdx.x, t = threadIdx.x;
  const double* p = part + (size_t)m * 1024;
  double s = p[t] + p[t + 256] + p[t + 512] + p[t + 768];
#pragma unroll
  for (int o = 32; o; o >>= 1) s += __shfl_down(s, o);
  __shared__ double red[4];
  if ((t & 63) == 0) red[t >> 6] = s;
  __syncthreads();
  if (t == 0) {
    double mean = (red[0] + red[1] + red[2] + red[3]) * (1.0 / 4194304.0);
    double cl = mean > 1e-5 ? mean : 1e-5;
    wqs[m] = 1.0 / cl;
    wmul[m] = (float)cl;
  }
}

__global__ __launch_bounds__(256) void k_wquant(Ptrs8 wsrc, const double* wqs, int8_t* wq) {
  int m = blockIdx.y;
  double qs = wqs[m];
  size_t base = (size_t)blockIdx.x * 4096 + threadIdx.x * 16;
  const float4* w4 = (const float4*)(wsrc.p[m] + base);
  union { int8_t b[16]; int4 v; } u;
#pragma unroll
  for (int j = 0; j < 4; ++j) {
    float4 v = w4[j];
    float f[4] = {v.x, v.y, v.z, v.w};
#pragma unroll
    for (int c = 0; c < 4; ++c) {
      int q = (int)rint((double)f[c] * qs);
      q = q > 1 ? 1 : (q < -1 ? -1 : q);
      u.b[j * 4 + c] = (int8_t)q;
    }
  }
  *(int4*)(wq + (size_t)m * 4194304 + base) = u.v;
}

// ---------------- activation rmsnorm + int8 quant ----------------
__global__ __launch_bounds__(256) void k_actq(const float* __restrict__ x, int8_t* __restrict__ q,
                                              float* __restrict__ inv) {
  int row = blockIdx.x, t = threadIdx.x;
  const float4* xr = (const float4*)(x + (size_t)row * D2);
  float4 a = xr[t * 2], b = xr[t * 2 + 1];
  float v[8] = {a.x, a.y, a.z, a.w, b.x, b.y, b.z, b.w};
  float ss = 0.f, ma = 0.f;
#pragma unroll
  for (int j = 0; j < 8; ++j) { ss += v[j] * v[j]; ma = fmaxf(ma, fabsf(v[j])); }
#pragma unroll
  for (int o = 32; o; o >>= 1) { ss += __shfl_down(ss, o); ma = fmaxf(ma, __shfl_down(ma, o)); }
  __shared__ float rs[4], rm[4], bc[2];
  if ((t & 63) == 0) { rs[t >> 6] = ss; rm[t >> 6] = ma; }
  __syncthreads();
  if (t == 0) {
    float S = rs[0] + rs[1] + rs[2] + rs[3];
    float M = fmaxf(fmaxf(rm[0], rm[1]), fmaxf(rm[2], rm[3]));
    float r = 1.0f / sqrtf(S * (1.0f / 2048.0f) + 1e-5f);
    float mx = fmaxf(M * r, 1e-5f);
    bc[0] = r;
    bc[1] = 127.0f / mx;
    inv[row] = mx * (1.0f / 127.0f);
  }
  __syncthreads();
  float r = bc[0], s = bc[1];
  union { int8_t b8[8]; int2 p2; } u;
#pragma unroll
  for (int j = 0; j < 8; ++j) {
    float xn = v[j] * r;
    int qq = (int)rintf(xn * s);
    qq = qq > 127 ? 127 : (qq < -128 ? -128 : qq);
    u.b8[j] = (int8_t)qq;
  }
  ((int2*)(q + (size_t)row * D2))[t] = u.p2;
}

// ---------------- int8 GEMM main loop: m97-geometry, 16x16x64 MFMA, 4x4 frags/wave --------
// LDS: A[128][64B] @0, B[128][64B] @8192. 16B slots XOR-swizzled by ((row>>1)&3) via the
// pre-swizzled global source; fragment reads apply the same XOR -> lanes 0..7 of each
// service group touch all 32 banks exactly once (conflict-free ds_read_b128).
__device__ __forceinline__ void gemm_mainloop(const int8_t* __restrict__ Aq,
                                              const int8_t* __restrict__ Wq, int ga0, int ga1,
                                              int n0, int t, int8_t* lds, v4i acc[4][4]) {
  const int wid = t >> 6, lane = t & 63;
  const int wr = wid >> 1, wc = wid & 1;
  const int lr = lane & 15, lc = lane >> 4;
  const int arow = t >> 2;
  const int achk = ((t & 3) ^ ((arow >> 1) & 3)) * 16;
  const int8_t* agp0 = Aq + (size_t)ga0 * 2048 + achk;
  const int8_t* agp1 = Aq + (size_t)ga1 * 2048 + achk;
  const int8_t* bgp0 = Wq + (size_t)(n0 + arow) * 2048 + achk;
  const int8_t* bgp1 = Wq + (size_t)(n0 + 64 + arow) * 2048 + achk;
  int8_t* ldsA = lds;
  int8_t* ldsB = lds + 8192;
  const int sw = (lr >> 1) & 3;  // row-driven slot XOR (row base is multiple of 16)

#pragma unroll 1
  for (int k0 = 0; k0 < 2048; k0 += 64) {
    gload16(agp0, ldsA + wid * 1024);
    gload16(agp1, ldsA + 4096 + wid * 1024);
    gload16(bgp0, ldsB + wid * 1024);
    gload16(bgp1, ldsB + 4096 + wid * 1024);
    agp0 += 64; agp1 += 64; bgp0 += 64; bgp1 += 64;
    __syncthreads();
    v4i af[4], bf[4];
#pragma unroll
    for (int mi = 0; mi < 4; ++mi) {
      int r = wr * 64 + mi * 16 + lr;
      af[mi] = *(const v4i*)(ldsA + r * 64 + ((lc ^ sw) << 4));
      int rb = wc * 64 + mi * 16 + lr;
      bf[mi] = *(const v4i*)(ldsB + rb * 64 + ((lc ^ sw) << 4));
    }
#pragma unroll
    for (int mi = 0; mi < 4; ++mi)
#pragma unroll
      for (int ni = 0; ni < 4; ++ni)
        acc[mi][ni] = __builtin_amdgcn_mfma_i32_16x16x64_i8(af[mi], bf[ni], acc[mi][ni], 0, 0, 0);
    __syncthreads();
  }
}

// ---------------- int8 GEMM: C[M,2048] = Aq[M,2048] x Wq[2048,2048]^T ----------------
__global__ __launch_bounds__(256) void k_gemm(const int8_t* __restrict__ Aq,
                                              const float* __restrict__ ainv,
                                              const int8_t* __restrict__ Wq,
                                              const float* __restrict__ wmul, int widx,
                                              float* __restrict__ C, RowMap inm, RowMap outm,
                                              int nM) {
  __shared__ __align__(16) int8_t lds[16384];
  int mb, nb;
  gswz(nM, mb, nb);
  int m0 = mb * 128, n0 = nb * 128;
  int t = threadIdx.x;
  int lane = t & 63, wid = t >> 6;
  int wr = wid >> 1, wc = wid & 1;
  int lr = lane & 15, lc = lane >> 4;
  int ga0 = rmap(inm, m0 + (t >> 2));
  int ga1 = rmap(inm, m0 + 64 + (t >> 2));

  v4i acc[4][4] = {};
  gemm_mainloop(Aq, Wq, ga0, ga1, n0, t, lds, acc);

  float wm = wmul[widx];
#pragma unroll
  for (int mi = 0; mi < 4; ++mi) {
#pragma unroll
    for (int q = 0; q < 4; ++q) {
      int rin = wr * 64 + mi * 16 + lc * 4 + q;
      int ra = rmap(inm, m0 + rin);
      int rc = rmap(outm, m0 + rin);
      float s = ainv[ra] * wm;
#pragma unroll
      for (int ni = 0; ni < 4; ++ni) {
        C[(size_t)rc * 2048 + n0 + wc * 64 + ni * 16 + lr] = (float)acc[mi][ni][q] * s;
      }
    }
  }
}

// -------- f-GEMM with fused gate epilogue: reads raw i, writes ig (in place) + a=sigmoid(f) ----
__global__ __launch_bounds__(256) void k_gemm_f(const int8_t* __restrict__ Aq,
                                                const float* __restrict__ ainv,
                                                const int8_t* __restrict__ Wq,
                                                const float* __restrict__ wmul,
                                                float* __restrict__ IG, float* __restrict__ AD,
                                                int nM) {
  __shared__ __align__(16) int8_t lds[16384];
  int mb, nb;
  gswz(nM, mb, nb);
  int m0 = mb * 128, n0 = nb * 128;
  int t = threadIdx.x;
  int lane = t & 63, wid = t >> 6;
  int wr = wid >> 1, wc = wid & 1;
  int lr = lane & 15, lc = lane >> 4;
  int ga0 = m0 + (t >> 2);
  int ga1 = m0 + 64 + (t >> 2);

  v4i acc[4][4] = {};
  gemm_mainloop(Aq, Wq, ga0, ga1, n0, t, lds, acc);

  float wm = wmul[QW_F];
#pragma unroll
  for (int mi = 0; mi < 4; ++mi) {
#pragma unroll
    for (int q = 0; q < 4; ++q) {
      int rin = m0 + wr * 64 + mi * 16 + lc * 4 + q;
      float s = ainv[rin] * wm;
#pragma unroll
      for (int ni = 0; ni < 4; ++ni) {
        size_t idx = (size_t)rin * 2048 + n0 + wc * 64 + ni * 16 + lr;
        float fval = (float)acc[mi][ni][q] * s;
        float iv = IG[idx];
        float a = fsig(fval);
        float si = iv * fsig(iv);
        IG[idx] = si * (1.0f - a);
        AD[idx] = a;
      }
    }
  }
}

// ---------------- chunked linear recurrence (decay a, no transcendentals) ----------------
__global__ __launch_bounds__(256) void k_rec1(const float* __restrict__ ig,
                                              const float* __restrict__ ad,
                                              float* __restrict__ chA, float* __restrict__ chH) {
  int tid = blockIdx.x * 256 + threadIdx.x;
  int chain = tid & 8191;
  int c = tid >> 13;
  int b = chain >> 11, d = chain & 2047;
  size_t base = ((size_t)b * 4608 + (size_t)c * 72) * 2048 + d;
  float h = 0.f, P = 1.f;
  for (int s = 0; s < 72; ++s) {
    float av = ad[base];
    float iv = ig[base];
    h = av * h + iv;
    P *= av;
    base += 2048;
  }
  chA[(size_t)c * 8192 + chain] = P;
  chH[(size_t)c * 8192 + chain] = h;
}

__global__ __launch_bounds__(256) void k_rec2(const float* __restrict__ chA,
                                              const float* __restrict__ chH,
                                              float* __restrict__ chC) {
  int chain = blockIdx.x * 256 + threadIdx.x;
  float carry = 0.f;
  for (int c = 0; c < 64; ++c) {
    chC[(size_t)c * 8192 + chain] = carry;
    carry = chA[(size_t)c * 8192 + chain] * carry + chH[(size_t)c * 8192 + chain];
  }
}

__global__ __launch_bounds__(256) void k_rec3(float* __restrict__ io, const float* __restrict__ ad,
                                              const float* __restrict__ chC) {
  int tid = blockIdx.x * 256 + threadIdx.x;
  int chain = tid & 8191;
  int c = tid >> 13;
  int b = chain >> 11, d = chain & 2047;
  size_t base = ((size_t)b * 4608 + (size_t)c * 72) * 2048 + d;
  float h = chC[(size_t)c * 8192 + chain];
  for (int s = 0; s < 72; ++s) {
    float av = ad[base];
    float iv = io[base];
    h = av * h + iv;
    io[base] = h;
    base += 2048;
  }
}

// ------- fused per-head rmsnorm + g*sig(g) gating + full-row rmsnorm + int8 quant -------
__global__ __launch_bounds__(256) void k_hnq(const float* __restrict__ o,
                                             const float* __restrict__ g,
                                             const float* __restrict__ gnw,
                                             int8_t* __restrict__ q, float* __restrict__ inv) {
  int row = blockIdx.x, t = threadIdx.x;
  size_t base = (size_t)row * D2 + (size_t)t * 8;
  float4 a = *(const float4*)(o + base);
  float4 b = *(const float4*)(o + base + 4);
  float v[8] = {a.x, a.y, a.z, a.w, b.x, b.y, b.z, b.w};
  float ss = 0.f;
#pragma unroll
  for (int j = 0; j < 8; ++j) ss += v[j] * v[j];
  ss += __shfl_xor(ss, 1);
  ss += __shfl_xor(ss, 2);
  ss += __shfl_xor(ss, 4);
  ss += __shfl_xor(ss, 8);
  float r = 1.0f / sqrtf(ss * (1.0f / 128.0f) + 1e-5f);
  float4 ga = *(const float4*)(g + base);
  float4 gb = *(const float4*)(g + base + 4);
  float gv[8] = {ga.x, ga.y, ga.z, ga.w, gb.x, gb.y, gb.z, gb.w};
  int j0 = (t & 15) * 8;
  float o2[8];
#pragma unroll
  for (int j = 0; j < 8; ++j) {
    float gg = gv[j];
    o2[j] = v[j] * r * gnw[j0 + j] * gg * fsig(gg);
  }
  float ss2 = 0.f, ma = 0.f;
#pragma unroll
  for (int j = 0; j < 8; ++j) { ss2 += o2[j] * o2[j]; ma = fmaxf(ma, fabsf(o2[j])); }
#pragma unroll
  for (int off = 32; off; off >>= 1) {
    ss2 += __shfl_down(ss2, off);
    ma = fmaxf(ma, __shfl_down(ma, off));
  }
  __shared__ float rs[4], rm[4], bc[2];
  if ((t & 63) == 0) { rs[t >> 6] = ss2; rm[t >> 6] = ma; }
  __syncthreads();
  if (t == 0) {
    float S = rs[0] + rs[1] + rs[2] + rs[3];
    float M = fmaxf(fmaxf(rm[0], rm[1]), fmaxf(rm[2], rm[3]));
    float rr = 1.0f / sqrtf(S * (1.0f / 2048.0f) + 1e-5f);
    float mx = fmaxf(M * rr, 1e-5f);
    bc[0] = rr;
    bc[1] = 127.0f / mx;
    inv[row] = mx * (1.0f / 127.0f);
  }
  __syncthreads();
  float rr = bc[0], s = bc[1];
  union { int8_t b8[8]; int2 p2; } u;
#pragma unroll
  for (int j = 0; j < 8; ++j) {
    float xn = o2[j] * rr;
    int qq = (int)rintf(xn * s);
    qq = qq > 127 ? 127 : (qq < -128 ? -128 : qq);
    u.b8[j] = (int8_t)qq;
  }
  ((int2*)(q + (size_t)row * D2))[t] = u.p2;
}

// ---------------- launch ----------------
extern "C" void kernel_launch(void* const* d_in, const int* in_sizes, int n_in,
                              void* d_out, int out_size, void* d_ws, size_t ws_size,
                              hipStream_t stream) {
  const float* hid = (const float*)d_in[0];
  const float* enc = (const float*)d_in[1];
  const float* gnw = (const float*)d_in[14];
  Ptrs8 wp;
  wp.p[QW_Q] = (const float*)d_in[2];
  wp.p[QW_OUT] = (const float*)d_in[5];
  wp.p[QW_ADDQ] = (const float*)d_in[6];
  wp.p[QW_ADDOUT] = (const float*)d_in[9];
  wp.p[QW_I] = (const float*)d_in[10];
  wp.p[QW_F] = (const float*)d_in[11];
  wp.p[QW_G] = (const float*)d_in[12];
  wp.p[QW_O] = (const float*)d_in[13];
  float* out = (float*)d_out;

  char* ws = (char*)d_ws;
  float* bufA = (float*)ws;                       // q_joint -> i_raw -> ig -> o -> (freed)
  float* bufB = bufA + 37748736;                  // a=sigmoid(f) -> attn_out
  int8_t* actq = (int8_t*)(bufB + 37748736);
  int8_t* wq = actq + 37748736;
  float* ainv = (float*)(wq + 33554432);
  double* wpart = (double*)(ainv + 18432);
  double* wqs = wpart + 8192;
  float* wmul = (float*)(wqs + 8);
  float* chA = wmul + 8;
  float* chH = chA + 524288;
  float* chC = chH + 524288;
  if (ws_size < 379723872ULL) return;  // insufficient scratch

  RowMap idm{0x40000000, 0, 0};
  RowMap seqm{4096, 4608, 512};  // seq rows -> joint rows
  RowMap encm{512, 4608, 0};     // enc rows -> joint rows

  // 1. weight quantization (8 matrices)
  k_wabs<<<dim3(1024, 8), 256, 0, stream>>>(wp, wpart);
  k_wmean<<<8, 256, 0, stream>>>(wpart, wqs, wmul);
  k_wquant<<<dim3(1024, 8), 256, 0, stream>>>(wp, wqs, wq);
  // 2. quantize inputs
  k_actq<<<16384, 256, 0, stream>>>(hid, actq, ainv);
  k_actq<<<2048, 256, 0, stream>>>(enc, actq + (size_t)16384 * 2048, ainv + 16384);
  // 3. q_s, q_c -> q_joint (bufA)
  k_gemm<<<128 * 16, 256, 0, stream>>>(actq, ainv, wq + (size_t)QW_Q * 4194304, wmul, QW_Q,
                                       bufA, idm, seqm, 128);
  k_gemm<<<16 * 16, 256, 0, stream>>>(actq + (size_t)16384 * 2048, ainv + 16384,
                                      wq + (size_t)QW_ADDQ * 4194304, wmul, QW_ADDQ, bufA,
                                      idm, encm, 16);
  // 4. quantize q_joint
  k_actq<<<18432, 256, 0, stream>>>(bufA, actq, ainv);
  // 5. i (raw -> bufA), g (-> d_out), then f with fused gate (ig -> bufA, a -> bufB)
  k_gemm<<<144 * 16, 256, 0, stream>>>(actq, ainv, wq + (size_t)QW_I * 4194304, wmul, QW_I,
                                       bufA, idm, idm, 144);
  k_gemm<<<144 * 16, 256, 0, stream>>>(actq, ainv, wq + (size_t)QW_G * 4194304, wmul, QW_G,
                                       out, idm, idm, 144);
  k_gemm_f<<<144 * 16, 256, 0, stream>>>(actq, ainv, wq + (size_t)QW_F * 4194304, wmul,
                                         bufA, bufB, 144);
  // 6. recurrence (o overwrites bufA)
  k_rec1<<<2048, 256, 0, stream>>>(bufA, bufB, chA, chH);
  k_rec2<<<32, 256, 0, stream>>>(chA, chH, chC);
  k_rec3<<<2048, 256, 0, stream>>>(bufA, bufB, chC);
  // 7. fused per-head norm + gate + quantize (o in bufA, g in d_out)
  k_hnq<<<18432, 256, 0, stream>>>(bufA, out, gnw, actq, ainv);
  // 8. o-projection -> bufB
  k_gemm<<<144 * 16, 256, 0, stream>>>(actq, ainv, wq + (size_t)QW_O * 4194304, wmul, QW_O,
                                       bufB, idm, idm, 144);
  // 9. quantize attn_out
  k_actq<<<18432, 256, 0, stream>>>(bufB, actq, ainv);
  // 10. final projections -> d_out
  k_gemm<<<128 * 16, 256, 0, stream>>>(actq, ainv, wq + (size_t)QW_OUT * 4194304, wmul,
                                       QW_OUT, out, seqm, idm, 128);
  k_gemm<<<16 * 16, 256, 0, stream>>>(actq, ainv, wq + (size_t)QW_ADDOUT * 4194304, wmul,
                                      QW_ADDOUT, out + (size_t)33554432, encm, idm, 16);
}

// Round 5
// 1117.010 us; speedup vs baseline: 1.2043x; 1.2043x over previous
//
#include <hip/hip_runtime.h>
#include <math.h>
#include <stdint.h>

#define D2 2048

typedef int v4i __attribute__((ext_vector_type(4)));
typedef int v16i __attribute__((ext_vector_type(16)));

struct Ptrs8 { const float* p[8]; };
struct RowMap { int seg, jump, off; };

enum { QW_Q = 0, QW_OUT = 1, QW_ADDQ = 2, QW_ADDOUT = 3, QW_I = 4, QW_F = 5, QW_G = 6, QW_O = 7 };

__device__ __forceinline__ int rmap(RowMap m, int r) {
  return (r / m.seg) * m.jump + (r % m.seg) + m.off;
}

__device__ __forceinline__ void gload16(const void* g, void* l) {
  __builtin_amdgcn_global_load_lds((__attribute__((address_space(1))) void*)g,
                                   (__attribute__((address_space(3))) void*)l, 16, 0, 0);
}

__device__ __forceinline__ float fsig(float x) {
  return __builtin_amdgcn_rcpf(1.0f + __expf(-x));
}

// XCD-chunked bijective grid swizzle (nwg divisible by 8 for all our grids), n-fast
// within a chunk so one A-panel stays hot in each XCD's L2. nN == 16 always.
__device__ __forceinline__ void gswz(int nM, int& mb, int& nb) {
  int bid = blockIdx.x;
  int wg = (bid & 7) * (nM << 1) + (bid >> 3);
  mb = wg >> 4;
  nb = wg & 15;
}

// ---------------- weight quantization ----------------
__global__ __launch_bounds__(256) void k_wabs(Ptrs8 wsrc, double* part) {
  int m = blockIdx.y;
  const float4* w4 = (const float4*)(wsrc.p[m] + (size_t)blockIdx.x * 4096 + threadIdx.x * 16);
  double s = 0.0;
#pragma unroll
  for (int j = 0; j < 4; ++j) {
    float4 v = w4[j];
    s += (double)fabsf(v.x) + (double)fabsf(v.y) + (double)fabsf(v.z) + (double)fabsf(v.w);
  }
#pragma unroll
  for (int o = 32; o; o >>= 1) s += __shfl_down(s, o);
  __shared__ double red[4];
  if ((threadIdx.x & 63) == 0) red[threadIdx.x >> 6] = s;
  __syncthreads();
  if (threadIdx.x == 0) part[(size_t)m * 1024 + blockIdx.x] = red[0] + red[1] + red[2] + red[3];
}

__global__ __launch_bounds__(256) void k_wmean(const double* part, double* wqs, float* wmul) {
  int m = blockIdx.x, t = threadIdx.x;
  const double* p = part + (size_t)m * 1024;
  double s = p[t] + p[t + 256] + p[t + 512] + p[t + 768];
#pragma unroll
  for (int o = 32; o; o >>= 1) s += __shfl_down(s, o);
  __shared__ double red[4];
  if ((t & 63) == 0) red[t >> 6] = s;
  __syncthreads();
  if (t == 0) {
    double mean = (red[0] + red[1] + red[2] + red[3]) * (1.0 / 4194304.0);
    double cl = mean > 1e-5 ? mean : 1e-5;
    wqs[m] = 1.0 / cl;
    wmul[m] = (float)cl;
  }
}

__global__ __launch_bounds__(256) void k_wquant(Ptrs8 wsrc, const double* wqs, int8_t* wq) {
  int m = blockIdx.y;
  double qs = wqs[m];
  size_t base = (size_t)blockIdx.x * 4096 + threadIdx.x * 16;
  const float4* w4 = (const float4*)(wsrc.p[m] + base);
  union { int8_t b[16]; int4 v; } u;
#pragma unroll
  for (int j = 0; j < 4; ++j) {
    float4 v = w4[j];
    float f[4] = {v.x, v.y, v.z, v.w};
#pragma unroll
    for (int c = 0; c < 4; ++c) {
      int q = (int)rint((double)f[c] * qs);
      q = q > 1 ? 1 : (q < -1 ? -1 : q);
      u.b[j * 4 + c] = (int8_t)q;
    }
  }
  *(int4*)(wq + (size_t)m * 4194304 + base) = u.v;
}

// ---------------- activation rmsnorm + int8 quant ----------------
__global__ __launch_bounds__(256) void k_actq(const float* __restrict__ x, int8_t* __restrict__ q,
                                              float* __restrict__ inv) {
  int row = blockIdx.x, t = threadIdx.x;
  const float4* xr = (const float4*)(x + (size_t)row * D2);
  float4 a = xr[t * 2], b = xr[t * 2 + 1];
  float v[8] = {a.x, a.y, a.z, a.w, b.x, b.y, b.z, b.w};
  float ss = 0.f, ma = 0.f;
#pragma unroll
  for (int j = 0; j < 8; ++j) { ss += v[j] * v[j]; ma = fmaxf(ma, fabsf(v[j])); }
#pragma unroll
  for (int o = 32; o; o >>= 1) { ss += __shfl_down(ss, o); ma = fmaxf(ma, __shfl_down(ma, o)); }
  __shared__ float rs[4], rm[4], bc[2];
  if ((t & 63) == 0) { rs[t >> 6] = ss; rm[t >> 6] = ma; }
  __syncthreads();
  if (t == 0) {
    float S = rs[0] + rs[1] + rs[2] + rs[3];
    float M = fmaxf(fmaxf(rm[0], rm[1]), fmaxf(rm[2], rm[3]));
    float r = 1.0f / sqrtf(S * (1.0f / 2048.0f) + 1e-5f);
    float mx = fmaxf(M * r, 1e-5f);
    bc[0] = r;
    bc[1] = 127.0f / mx;
    inv[row] = mx * (1.0f / 127.0f);
  }
  __syncthreads();
  float r = bc[0], s = bc[1];
  union { int8_t b8[8]; int2 p2; } u;
#pragma unroll
  for (int j = 0; j < 8; ++j) {
    float xn = v[j] * r;
    int qq = (int)rintf(xn * s);
    qq = qq > 127 ? 127 : (qq < -128 ? -128 : qq);
    u.b8[j] = (int8_t)qq;
  }
  ((int2*)(q + (size_t)row * D2))[t] = u.p2;
}

// ---------------- int8 GEMM main loop: triple-buffered, counted-vmcnt pipeline ----------------
// LDS 48KB: {A,B} x 3 buffers of 8KB. Tile t uses buffer t%3. Staging for tile t+3 is
// issued right after tile t's barrier -> 4 loads always in flight ACROSS barriers
// (vmcnt(4) in steady state, never 0 until the tail). 16B slots XOR-swizzled by
// ((row>>1)&3) via the pre-swizzled global source; reads apply the same XOR ->
// conflict-free ds_read_b128 (verified: 0 conflicts in round 4).
#define SYNC_PIPE(N)                                          \
  do {                                                        \
    __builtin_amdgcn_sched_barrier(0);                        \
    asm volatile("s_waitcnt vmcnt(" #N ")" ::: "memory");     \
    __builtin_amdgcn_sched_barrier(0);                        \
    __builtin_amdgcn_s_barrier();                             \
    __builtin_amdgcn_sched_barrier(0);                        \
  } while (0)

__device__ __forceinline__ void gemm_mainloop(const int8_t* __restrict__ Aq,
                                              const int8_t* __restrict__ Wq, int ga0, int ga1,
                                              int n0, int t, int8_t* lds, v16i acc[2][2]) {
  const int wid = t >> 6, lane = t & 63;
  const int wr = wid >> 1, wc = wid & 1, am = lane & 31, g = lane >> 5;
  const int arow = t >> 2;
  const int achk = ((t & 3) ^ ((arow >> 1) & 3)) * 16;
  const int8_t* agp0 = Aq + (size_t)ga0 * 2048 + achk;
  const int8_t* agp1 = Aq + (size_t)ga1 * 2048 + achk;
  const int8_t* bgp0 = Wq + (size_t)(n0 + arow) * 2048 + achk;
  const int8_t* bgp1 = Wq + (size_t)(n0 + 64 + arow) * 2048 + achk;
  int8_t* A0 = lds;
  int8_t* B0 = lds + 8192;
  int8_t* A1 = lds + 16384;
  int8_t* B1 = lds + 24576;
  int8_t* A2 = lds + 32768;
  int8_t* B2 = lds + 40960;

#define STAGE(Ab, Bb)                                 \
  do {                                                \
    gload16(agp0, (Ab) + wid * 1024);                 \
    gload16(agp1, (Ab) + 4096 + wid * 1024);          \
    gload16(bgp0, (Bb) + wid * 1024);                 \
    gload16(bgp1, (Bb) + 4096 + wid * 1024);          \
    agp0 += 64; agp1 += 64; bgp0 += 64; bgp1 += 64;   \
  } while (0)

#define COMPUTE(Ab, Bb)                                                                     \
  do {                                                                                      \
    _Pragma("unroll") for (int kk = 0; kk < 2; ++kk) {                                      \
      v4i af[2], bf[2];                                                                     \
      _Pragma("unroll") for (int mi = 0; mi < 2; ++mi) {                                    \
        int r = wr * 64 + mi * 32 + am;                                                     \
        int slot = ((kk << 1) | g) ^ ((r >> 1) & 3);                                        \
        af[mi] = *(const v4i*)((Ab) + r * 64 + slot * 16);                                  \
        int rb = wc * 64 + mi * 32 + am;                                                    \
        int slotb = ((kk << 1) | g) ^ ((rb >> 1) & 3);                                      \
        bf[mi] = *(const v4i*)((Bb) + rb * 64 + slotb * 16);                                \
      }                                                                                     \
      _Pragma("unroll") for (int mi = 0; mi < 2; ++mi)                                      \
        _Pragma("unroll") for (int ni = 0; ni < 2; ++ni)                                    \
          acc[mi][ni] =                                                                     \
              __builtin_amdgcn_mfma_i32_32x32x32_i8(af[mi], bf[ni], acc[mi][ni], 0, 0, 0);  \
    }                                                                                       \
  } while (0)

  // prologue: 3 tiles in flight (12 loads)
  STAGE(A0, B0);
  STAGE(A1, B1);
  STAGE(A2, B2);
  SYNC_PIPE(8);  // tile 0 resident everywhere; tiles 1,2 in flight
#pragma unroll 1
  for (int tt = 0; tt < 30; tt += 3) {
    COMPUTE(A0, B0);                    // tile tt
    SYNC_PIPE(4);                       // tile tt+1 resident; tt+2 in flight
    if (tt + 3 < 32) STAGE(A0, B0);     // stage tile tt+3
    COMPUTE(A1, B1);                    // tile tt+1
    SYNC_PIPE(4);
    if (tt + 4 < 32) STAGE(A1, B1);
    COMPUTE(A2, B2);                    // tile tt+2
    SYNC_PIPE(4);
    if (tt + 5 < 32) STAGE(A2, B2);
  }
  COMPUTE(A0, B0);  // tile 30
  SYNC_PIPE(0);     // tile 31 resident
  COMPUTE(A1, B1);  // tile 31
#undef STAGE
#undef COMPUTE
}

// ---------------- int8 GEMM: C[M,2048] = Aq[M,2048] x Wq[2048,2048]^T ----------------
__global__ __launch_bounds__(256) void k_gemm(const int8_t* __restrict__ Aq,
                                              const float* __restrict__ ainv,
                                              const int8_t* __restrict__ Wq,
                                              const float* __restrict__ wmul, int widx,
                                              float* __restrict__ C, RowMap inm, RowMap outm,
                                              int nM) {
  __shared__ __align__(16) int8_t lds[49152];
  int mb, nb;
  gswz(nM, mb, nb);
  int m0 = mb * 128, n0 = nb * 128;
  int t = threadIdx.x;
  int lane = t & 63, wid = t >> 6;
  int wr = wid >> 1, wc = wid & 1;
  int am = lane & 31, g = lane >> 5;
  int ga0 = rmap(inm, m0 + (t >> 2));
  int ga1 = rmap(inm, m0 + 64 + (t >> 2));

  v16i acc[2][2] = {};
  gemm_mainloop(Aq, Wq, ga0, ga1, n0, t, lds, acc);

  float wm = wmul[widx];
#pragma unroll
  for (int mi = 0; mi < 2; ++mi) {
#pragma unroll
    for (int q = 0; q < 16; ++q) {
      int rin = wr * 64 + mi * 32 + (q & 3) + ((q >> 2) * 8) + g * 4;
      int ra = rmap(inm, m0 + rin);
      int rc = rmap(outm, m0 + rin);
      float s = ainv[ra] * wm;
#pragma unroll
      for (int ni = 0; ni < 2; ++ni) {
        C[(size_t)rc * 2048 + n0 + wc * 64 + ni * 32 + am] = (float)acc[mi][ni][q] * s;
      }
    }
  }
}

// -------- f-GEMM with fused gate epilogue: reads raw i, writes ig (in place) + a=sigmoid(f) ----
__global__ __launch_bounds__(256) void k_gemm_f(const int8_t* __restrict__ Aq,
                                                const float* __restrict__ ainv,
                                                const int8_t* __restrict__ Wq,
                                                const float* __restrict__ wmul,
                                                float* __restrict__ IG, float* __restrict__ AD,
                                                int nM) {
  __shared__ __align__(16) int8_t lds[49152];
  int mb, nb;
  gswz(nM, mb, nb);
  int m0 = mb * 128, n0 = nb * 128;
  int t = threadIdx.x;
  int lane = t & 63, wid = t >> 6;
  int wr = wid >> 1, wc = wid & 1;
  int am = lane & 31, g = lane >> 5;
  int ga0 = m0 + (t >> 2);
  int ga1 = m0 + 64 + (t >> 2);

  v16i acc[2][2] = {};
  gemm_mainloop(Aq, Wq, ga0, ga1, n0, t, lds, acc);

  float wm = wmul[QW_F];
#pragma unroll
  for (int mi = 0; mi < 2; ++mi) {
#pragma unroll
    for (int q = 0; q < 16; ++q) {
      int rin = m0 + wr * 64 + mi * 32 + (q & 3) + ((q >> 2) * 8) + g * 4;
      float s = ainv[rin] * wm;
#pragma unroll
      for (int ni = 0; ni < 2; ++ni) {
        size_t idx = (size_t)rin * 2048 + n0 + wc * 64 + ni * 32 + am;
        float fval = (float)acc[mi][ni][q] * s;
        float iv = IG[idx];
        float a = fsig(fval);
        float si = iv * fsig(iv);
        IG[idx] = si * (1.0f - a);
        AD[idx] = a;
      }
    }
  }
}

// ---------------- chunked linear recurrence (decay a, no transcendentals) ----------------
__global__ __launch_bounds__(256) void k_rec1(const float* __restrict__ ig,
                                              const float* __restrict__ ad,
                                              float* __restrict__ chA, float* __restrict__ chH) {
  int tid = blockIdx.x * 256 + threadIdx.x;
  int chain = tid & 8191;
  int c = tid >> 13;
  int b = chain >> 11, d = chain & 2047;
  size_t base = ((size_t)b * 4608 + (size_t)c * 72) * 2048 + d;
  float h = 0.f, P = 1.f;
  for (int s = 0; s < 72; ++s) {
    float av = ad[base];
    float iv = ig[base];
    h = av * h + iv;
    P *= av;
    base += 2048;
  }
  chA[(size_t)c * 8192 + chain] = P;
  chH[(size_t)c * 8192 + chain] = h;
}

__global__ __launch_bounds__(256) void k_rec2(const float* __restrict__ chA,
                                              const float* __restrict__ chH,
                                              float* __restrict__ chC) {
  int chain = blockIdx.x * 256 + threadIdx.x;
  float carry = 0.f;
  for (int c = 0; c < 64; ++c) {
    chC[(size_t)c * 8192 + chain] = carry;
    carry = chA[(size_t)c * 8192 + chain] * carry + chH[(size_t)c * 8192 + chain];
  }
}

__global__ __launch_bounds__(256) void k_rec3(float* __restrict__ io, const float* __restrict__ ad,
                                              const float* __restrict__ chC) {
  int tid = blockIdx.x * 256 + threadIdx.x;
  int chain = tid & 8191;
  int c = tid >> 13;
  int b = chain >> 11, d = chain & 2047;
  size_t base = ((size_t)b * 4608 + (size_t)c * 72) * 2048 + d;
  float h = chC[(size_t)c * 8192 + chain];
  for (int s = 0; s < 72; ++s) {
    float av = ad[base];
    float iv = io[base];
    h = av * h + iv;
    io[base] = h;
    base += 2048;
  }
}

// ------- fused per-head rmsnorm + g*sig(g) gating + full-row rmsnorm + int8 quant -------
__global__ __launch_bounds__(256) void k_hnq(const float* __restrict__ o,
                                             const float* __restrict__ g,
                                             const float* __restrict__ gnw,
                                             int8_t* __restrict__ q, float* __restrict__ inv) {
  int row = blockIdx.x, t = threadIdx.x;
  size_t base = (size_t)row * D2 + (size_t)t * 8;
  float4 a = *(const float4*)(o + base);
  float4 b = *(const float4*)(o + base + 4);
  float v[8] = {a.x, a.y, a.z, a.w, b.x, b.y, b.z, b.w};
  float ss = 0.f;
#pragma unroll
  for (int j = 0; j < 8; ++j) ss += v[j] * v[j];
  ss += __shfl_xor(ss, 1);
  ss += __shfl_xor(ss, 2);
  ss += __shfl_xor(ss, 4);
  ss += __shfl_xor(ss, 8);
  float r = 1.0f / sqrtf(ss * (1.0f / 128.0f) + 1e-5f);
  float4 ga = *(const float4*)(g + base);
  float4 gb = *(const float4*)(g + base + 4);
  float gv[8] = {ga.x, ga.y, ga.z, ga.w, gb.x, gb.y, gb.z, gb.w};
  int j0 = (t & 15) * 8;
  float o2[8];
#pragma unroll
  for (int j = 0; j < 8; ++j) {
    float gg = gv[j];
    o2[j] = v[j] * r * gnw[j0 + j] * gg * fsig(gg);
  }
  float ss2 = 0.f, ma = 0.f;
#pragma unroll
  for (int j = 0; j < 8; ++j) { ss2 += o2[j] * o2[j]; ma = fmaxf(ma, fabsf(o2[j])); }
#pragma unroll
  for (int off = 32; off; off >>= 1) {
    ss2 += __shfl_down(ss2, off);
    ma = fmaxf(ma, __shfl_down(ma, off));
  }
  __shared__ float rs[4], rm[4], bc[2];
  if ((t & 63) == 0) { rs[t >> 6] = ss2; rm[t >> 6] = ma; }
  __syncthreads();
  if (t == 0) {
    float S = rs[0] + rs[1] + rs[2] + rs[3];
    float M = fmaxf(fmaxf(rm[0], rm[1]), fmaxf(rm[2], rm[3]));
    float rr = 1.0f / sqrtf(S * (1.0f / 2048.0f) + 1e-5f);
    float mx = fmaxf(M * rr, 1e-5f);
    bc[0] = rr;
    bc[1] = 127.0f / mx;
    inv[row] = mx * (1.0f / 127.0f);
  }
  __syncthreads();
  float rr = bc[0], s = bc[1];
  union { int8_t b8[8]; int2 p2; } u;
#pragma unroll
  for (int j = 0; j < 8; ++j) {
    float xn = o2[j] * rr;
    int qq = (int)rintf(xn * s);
    qq = qq > 127 ? 127 : (qq < -128 ? -128 : qq);
    u.b8[j] = (int8_t)qq;
  }
  ((int2*)(q + (size_t)row * D2))[t] = u.p2;
}

// ---------------- launch ----------------
extern "C" void kernel_launch(void* const* d_in, const int* in_sizes, int n_in,
                              void* d_out, int out_size, void* d_ws, size_t ws_size,
                              hipStream_t stream) {
  const float* hid = (const float*)d_in[0];
  const float* enc = (const float*)d_in[1];
  const float* gnw = (const float*)d_in[14];
  Ptrs8 wp;
  wp.p[QW_Q] = (const float*)d_in[2];
  wp.p[QW_OUT] = (const float*)d_in[5];
  wp.p[QW_ADDQ] = (const float*)d_in[6];
  wp.p[QW_ADDOUT] = (const float*)d_in[9];
  wp.p[QW_I] = (const float*)d_in[10];
  wp.p[QW_F] = (const float*)d_in[11];
  wp.p[QW_G] = (const float*)d_in[12];
  wp.p[QW_O] = (const float*)d_in[13];
  float* out = (float*)d_out;

  char* ws = (char*)d_ws;
  float* bufA = (float*)ws;                       // q_joint -> i_raw -> ig -> o -> (freed)
  float* bufB = bufA + 37748736;                  // a=sigmoid(f) -> attn_out
  int8_t* actq = (int8_t*)(bufB + 37748736);
  int8_t* wq = actq + 37748736;
  float* ainv = (float*)(wq + 33554432);
  double* wpart = (double*)(ainv + 18432);
  double* wqs = wpart + 8192;
  float* wmul = (float*)(wqs + 8);
  float* chA = wmul + 8;
  float* chH = chA + 524288;
  float* chC = chH + 524288;
  if (ws_size < 379723872ULL) return;  // insufficient scratch

  RowMap idm{0x40000000, 0, 0};
  RowMap seqm{4096, 4608, 512};  // seq rows -> joint rows
  RowMap encm{512, 4608, 0};     // enc rows -> joint rows

  // 1. weight quantization (8 matrices)
  k_wabs<<<dim3(1024, 8), 256, 0, stream>>>(wp, wpart);
  k_wmean<<<8, 256, 0, stream>>>(wpart, wqs, wmul);
  k_wquant<<<dim3(1024, 8), 256, 0, stream>>>(wp, wqs, wq);
  // 2. quantize inputs
  k_actq<<<16384, 256, 0, stream>>>(hid, actq, ainv);
  k_actq<<<2048, 256, 0, stream>>>(enc, actq + (size_t)16384 * 2048, ainv + 16384);
  // 3. q_s, q_c -> q_joint (bufA)
  k_gemm<<<128 * 16, 256, 0, stream>>>(actq, ainv, wq + (size_t)QW_Q * 4194304, wmul, QW_Q,
                                       bufA, idm, seqm, 128);
  k_gemm<<<16 * 16, 256, 0, stream>>>(actq + (size_t)16384 * 2048, ainv + 16384,
                                      wq + (size_t)QW_ADDQ * 4194304, wmul, QW_ADDQ, bufA,
                                      idm, encm, 16);
  // 4. quantize q_joint
  k_actq<<<18432, 256, 0, stream>>>(bufA, actq, ainv);
  // 5. i (raw -> bufA), g (-> d_out), then f with fused gate (ig -> bufA, a -> bufB)
  k_gemm<<<144 * 16, 256, 0, stream>>>(actq, ainv, wq + (size_t)QW_I * 4194304, wmul, QW_I,
                                       bufA, idm, idm, 144);
  k_gemm<<<144 * 16, 256, 0, stream>>>(actq, ainv, wq + (size_t)QW_G * 4194304, wmul, QW_G,
                                       out, idm, idm, 144);
  k_gemm_f<<<144 * 16, 256, 0, stream>>>(actq, ainv, wq + (size_t)QW_F * 4194304, wmul,
                                         bufA, bufB, 144);
  // 6. recurrence (o overwrites bufA)
  k_rec1<<<2048, 256, 0, stream>>>(bufA, bufB, chA, chH);
  k_rec2<<<32, 256, 0, stream>>>(chA, chH, chC);
  k_rec3<<<2048, 256, 0, stream>>>(bufA, bufB, chC);
  // 7. fused per-head norm + gate + quantize (o in bufA, g in d_out)
  k_hnq<<<18432, 256, 0, stream>>>(bufA, out, gnw, actq, ainv);
  // 8. o-projection -> bufB
  k_gemm<<<144 * 16, 256, 0, stream>>>(actq, ainv, wq + (size_t)QW_O * 4194304, wmul, QW_O,
                                       bufB, idm, idm, 144);
  // 9. quantize attn_out
  k_actq<<<18432, 256, 0, stream>>>(bufB, actq, ainv);
  // 10. final projections -> d_out
  k_gemm<<<128 * 16, 256, 0, stream>>>(actq, ainv, wq + (size_t)QW_OUT * 4194304, wmul,
                                       QW_OUT, out, seqm, idm, 128);
  k_gemm<<<16 * 16, 256, 0, stream>>>(actq, ainv, wq + (size_t)QW_ADDOUT * 4194304, wmul,
                                      QW_ADDOUT, out + (size_t)33554432, encm, idm, 16);
}